// Round 1
// baseline (2459.751 us; speedup 1.0000x reference)
//
#include <hip/hip_runtime.h>
#include <math.h>

#define EMBED 1024
#define NHEADS 16
#define HDIM 64
#define BATCH 4
#define SQL 1024
#define SKL 2048
#define QSCALE 0.125f   // 1/sqrt(64)

// ---------------------------------------------------------------------------
// GEMM (NT): Y[M,N] = X[M,K] * W[N,K]^T + bias[N],  K = N = 1024.
// 128x128 tile, BK=16, 256 threads, 8x8 microtile, fp32.
// ---------------------------------------------------------------------------
__global__ __launch_bounds__(256)
void gemm_nt_bias(const float* __restrict__ X, const float* __restrict__ W,
                  const float* __restrict__ bias, float* __restrict__ Y,
                  int M) {
    const int K = 1024, N = 1024;
    __shared__ float Xs[16][132];   // [k][m], pad 132 keeps 16B alignment of rows
    __shared__ float Ws[16][132];   // [k][n]

    const int tid = threadIdx.x;
    const int tx = tid & 15;        // n microtile
    const int ty = tid >> 4;        // m microtile
    const int rowBase = blockIdx.y * 128;
    const int colBase = blockIdx.x * 128;

    const int sr = tid >> 1;        // 0..127 staging row
    const int sc = (tid & 1) * 8;   // 0 or 8 staging col group

    float acc[8][8];
#pragma unroll
    for (int i = 0; i < 8; ++i)
#pragma unroll
        for (int j = 0; j < 8; ++j) acc[i][j] = 0.f;

    for (int k0 = 0; k0 < K; k0 += 16) {
        if (k0) __syncthreads();
        float4 a0 = *(const float4*)&X[(size_t)(rowBase + sr) * K + k0 + sc];
        float4 a1 = *(const float4*)&X[(size_t)(rowBase + sr) * K + k0 + sc + 4];
        float4 b0 = *(const float4*)&W[(size_t)(colBase + sr) * K + k0 + sc];
        float4 b1 = *(const float4*)&W[(size_t)(colBase + sr) * K + k0 + sc + 4];
        Xs[sc + 0][sr] = a0.x; Xs[sc + 1][sr] = a0.y;
        Xs[sc + 2][sr] = a0.z; Xs[sc + 3][sr] = a0.w;
        Xs[sc + 4][sr] = a1.x; Xs[sc + 5][sr] = a1.y;
        Xs[sc + 6][sr] = a1.z; Xs[sc + 7][sr] = a1.w;
        Ws[sc + 0][sr] = b0.x; Ws[sc + 1][sr] = b0.y;
        Ws[sc + 2][sr] = b0.z; Ws[sc + 3][sr] = b0.w;
        Ws[sc + 4][sr] = b1.x; Ws[sc + 5][sr] = b1.y;
        Ws[sc + 6][sr] = b1.z; Ws[sc + 7][sr] = b1.w;
        __syncthreads();

#pragma unroll
        for (int kk = 0; kk < 16; ++kk) {
            float4 x0 = *(float4*)&Xs[kk][ty * 8];
            float4 x1 = *(float4*)&Xs[kk][ty * 8 + 4];
            float4 w0 = *(float4*)&Ws[kk][tx * 8];
            float4 w1 = *(float4*)&Ws[kk][tx * 8 + 4];
            float xv[8] = {x0.x, x0.y, x0.z, x0.w, x1.x, x1.y, x1.z, x1.w};
            float wv[8] = {w0.x, w0.y, w0.z, w0.w, w1.x, w1.y, w1.z, w1.w};
#pragma unroll
            for (int i = 0; i < 8; ++i)
#pragma unroll
                for (int j = 0; j < 8; ++j) acc[i][j] += xv[i] * wv[j];
        }
    }

    float bl[8];
#pragma unroll
    for (int j = 0; j < 8; ++j) bl[j] = bias[colBase + tx * 8 + j];
#pragma unroll
    for (int i = 0; i < 8; ++i) {
        int row = rowBase + ty * 8 + i;
        float4 o0 = make_float4(acc[i][0] + bl[0], acc[i][1] + bl[1],
                                acc[i][2] + bl[2], acc[i][3] + bl[3]);
        float4 o1 = make_float4(acc[i][4] + bl[4], acc[i][5] + bl[5],
                                acc[i][6] + bl[6], acc[i][7] + bl[7]);
        *(float4*)&Y[(size_t)row * N + colBase + tx * 8] = o0;
        *(float4*)&Y[(size_t)row * N + colBase + tx * 8 + 4] = o1;
    }
}

// ---------------------------------------------------------------------------
// Fused attention: per block = (b, 16 q-rows). Loops over 16 heads.
// Single-pass softmax (no max subtraction needed: |scores| <= ~20).
// e-values parked in the block's own slice of meanOut (scratch), mean
// accumulated across heads in 128KB LDS, finalized at the end.
// 512 threads (8 waves), grid = 4*64 = 256 blocks = 1 block/CU.
// ---------------------------------------------------------------------------
__global__ __launch_bounds__(512)
void attn_fused(const float* __restrict__ Qw, const float* __restrict__ Kw,
                const float* __restrict__ Vw, float* __restrict__ attOut,
                float* __restrict__ meanOut) {
    __shared__ float meanacc[16][2048];   // 128 KB
    __shared__ float Qs[16][68];
    __shared__ float Ks[32][68];
    __shared__ float Vs[32][68];
    __shared__ float Ps[16][32];
    __shared__ float linv_sh[16];

    const int t = threadIdx.x;
    const int b = blockIdx.x >> 6;
    const int qt = blockIdx.x & 63;
    const int qbase = qt * 16;

    const int qi = t >> 5;          // 0..15 (score & PV row)
    const int kj = t & 31;          // 0..31 (score col in chunk)
    const int dg = t & 31;          // 0..31 (PV dim pair: dims 2dg, 2dg+1)
    const int sr = t >> 4;          // 0..31 (staging row)
    const int sc4 = (t & 15) * 4;   // staging col (float4)

    // this block's exclusive slice of mean output (also used as e-scratch)
    float* meanScratch = meanOut + (size_t)(b * SQL + qbase) * SKL;

    // zero the mean accumulator
#pragma unroll
    for (int i = 0; i < 16; ++i)
        *(float4*)&meanacc[i][t * 4] = make_float4(0.f, 0.f, 0.f, 0.f);

    for (int h = 0; h < NHEADS; ++h) {
        __syncthreads();   // meanacc init / prev phase B done; Qs safe to write
        if (t < 256) {
            int qr = t >> 4, qc = (t & 15) * 4;
            float4 q4 = *(const float4*)&Qw[(size_t)(b * SQL + qbase + qr) * EMBED + h * HDIM + qc];
            Qs[qr][qc + 0] = q4.x; Qs[qr][qc + 1] = q4.y;
            Qs[qr][qc + 2] = q4.z; Qs[qr][qc + 3] = q4.w;
        }
        float l_loc = 0.f;
        float au0 = 0.f, au1 = 0.f;
        __syncthreads();   // Qs ready; prev head's PV done with Ks/Vs

        for (int c = 0; c < SKL / 32; ++c) {
            const int kbase = c * 32;
            // stage K,V chunk (32 rows x 64 dims)
            float4 k4 = *(const float4*)&Kw[(size_t)(b * SKL + kbase + sr) * EMBED + h * HDIM + sc4];
            float4 v4 = *(const float4*)&Vw[(size_t)(b * SKL + kbase + sr) * EMBED + h * HDIM + sc4];
            *(float4*)&Ks[sr][sc4] = k4;
            *(float4*)&Vs[sr][sc4] = v4;
            __syncthreads();

            // scores: thread (qi,kj) -> one score
            float s = 0.f;
#pragma unroll
            for (int d4 = 0; d4 < 64; d4 += 4) {
                float4 q4 = *(float4*)&Qs[qi][d4];
                float4 kk4 = *(float4*)&Ks[kj][d4];
                s += q4.x * kk4.x + q4.y * kk4.y + q4.z * kk4.z + q4.w * kk4.w;
            }
            float e = __expf(s * QSCALE);
            l_loc += e;
            Ps[qi][kj] = e;
            meanScratch[(size_t)qi * SKL + kbase + kj] = e;  // unnormalized park
            __syncthreads();

            // PV: thread (qi,dg) accumulates dims {2dg, 2dg+1}
#pragma unroll
            for (int k = 0; k < 32; ++k) {
                float p = Ps[qi][k];
                float2 v2 = *(float2*)&Vs[k][dg * 2];
                au0 += p * v2.x;
                au1 += p * v2.y;
            }
            __syncthreads();   // protect Ks/Vs/Ps before next stage
        }

        // reduce l over the 32 kj-lanes per row
        Ps[qi][kj] = l_loc;
        __syncthreads();
        if (t < 16) {
            float sum = 0.f;
            for (int j = 0; j < 32; ++j) sum += Ps[t][j];
            linv_sh[t] = 1.0f / sum;
        }
        __syncthreads();

        // write attended (normalized) for this head
        float li = linv_sh[qi];
        float2 av = make_float2(au0 * li, au1 * li);
        *(float2*)&attOut[(size_t)(b * SQL + qbase + qi) * EMBED + h * HDIM + dg * 2] = av;

        // phase B: meanacc += e * (1/l) from the parked scratch (L2-hot)
#pragma unroll
        for (int i = 0; i < 16; ++i) {
            float4 e4 = *(const float4*)&meanScratch[(size_t)i * SKL + t * 4];
            float liB = linv_sh[i];
            float4 m4 = *(float4*)&meanacc[i][t * 4];
            m4.x += e4.x * liB; m4.y += e4.y * liB;
            m4.z += e4.z * liB; m4.w += e4.w * liB;
            *(float4*)&meanacc[i][t * 4] = m4;
        }
    }

    __syncthreads();
    const float inv16 = 1.0f / 16.0f;
#pragma unroll
    for (int i = 0; i < 16; ++i) {
        float4 m4 = *(float4*)&meanacc[i][t * 4];
        m4.x *= inv16; m4.y *= inv16; m4.z *= inv16; m4.w *= inv16;
        *(float4*)&meanOut[(size_t)(b * SQL + qbase + i) * SKL + t * 4] = m4;
    }
}

// ---------------------------------------------------------------------------
extern "C" void kernel_launch(void* const* d_in, const int* in_sizes, int n_in,
                              void* d_out, int out_size, void* d_ws, size_t ws_size,
                              hipStream_t stream) {
    const float* query = (const float*)d_in[0];
    const float* key   = (const float*)d_in[1];
    const float* value = (const float*)d_in[2];
    const float* Wq = (const float*)d_in[3];
    const float* bq = (const float*)d_in[4];
    const float* Wk = (const float*)d_in[5];
    const float* bk = (const float*)d_in[6];
    const float* Wv = (const float*)d_in[7];
    const float* bv = (const float*)d_in[8];
    const float* Wo = (const float*)d_in[9];
    const float* bo = (const float*)d_in[10];

    float* out = (float*)d_out;                                  // [4,1024,1024]
    float* meanOut = out + (size_t)BATCH * SQL * EMBED;          // [4,1024,2048]

    float* ws  = (float*)d_ws;
    float* Qws = ws;                                             // 4096x1024
    float* Kws = Qws + (size_t)BATCH * SQL * EMBED;              // 8192x1024
    float* Vws = Kws + (size_t)BATCH * SKL * EMBED;              // 8192x1024
    float* Aws = Vws + (size_t)BATCH * SKL * EMBED;              // 4096x1024

    dim3 blk(256);
    gemm_nt_bias<<<dim3(8, 4096 / 128), blk, 0, stream>>>(query, Wq, bq, Qws, 4096);
    gemm_nt_bias<<<dim3(8, 8192 / 128), blk, 0, stream>>>(key,   Wk, bk, Kws, 8192);
    gemm_nt_bias<<<dim3(8, 8192 / 128), blk, 0, stream>>>(value, Wv, bv, Vws, 8192);

    attn_fused<<<dim3(256), dim3(512), 0, stream>>>(Qws, Kws, Vws, Aws, meanOut);

    gemm_nt_bias<<<dim3(8, 4096 / 128), blk, 0, stream>>>(Aws, Wo, bo, out, 4096);
}

// Round 2
// 621.413 us; speedup vs baseline: 3.9583x; 3.9583x over previous
//
#include <hip/hip_runtime.h>
#include <hip/hip_bf16.h>
#include <math.h>

#define EMBED 1024
#define NHEADS 16
#define HDIM 64
#define BATCH 4
#define SQL 1024
#define SKL 2048

typedef unsigned short u16;
typedef __attribute__((ext_vector_type(4))) float f32x4;
typedef __attribute__((ext_vector_type(8))) __bf16 bf16x8;
typedef __attribute__((ext_vector_type(8))) short s16x8;
typedef __attribute__((ext_vector_type(8))) u16 u16x8;

__device__ __forceinline__ u16 f2bf(float x) {
    __hip_bfloat16 h = __float2bfloat16(x);
    return *reinterpret_cast<u16*>(&h);
}
__device__ __forceinline__ float bf2f(u16 u) {
    __hip_bfloat16 h;
    *reinterpret_cast<u16*>(&h) = u;
    return __bfloat162float(h);
}
__device__ __forceinline__ f32x4 mfma16(s16x8 a, s16x8 b, f32x4 c) {
    return __builtin_amdgcn_mfma_f32_16x16x32_bf16(
        __builtin_bit_cast(bf16x8, a), __builtin_bit_cast(bf16x8, b), c, 0, 0, 0);
}
__device__ __forceinline__ void gload16(const void* g, void* l) {
    __builtin_amdgcn_global_load_lds(
        (const __attribute__((address_space(1))) void*)g,
        (__attribute__((address_space(3))) void*)l, 16, 0, 0);
}

// ---------------------------------------------------------------------------
// GEMM NT: Y[M,N] = A[M,K] * W[N,K]^T + bias.  K=1024. 128x128 tile, BK=32,
// 256 thr (4 waves), wave -> 64x64 (4x4 16x16 frags). Reg-staged (fp32->bf16
// cvt during staging), padded LDS rows (40 u16 = 5*16B -> conflict-free).
// SPLIT: A,W staged as hi+lo bf16 planes; 3 MFMAs per frag pair (fp32-like).
// OUT_MODE 0: f32 Y0 + bias[col]; 1: bf16 hi->Y0, lo->Y1 + bias[col];
//          2: bf16 Y0 + bias[row].
// ---------------------------------------------------------------------------
template<int SPLIT, int A_BF16, int OUT_MODE>
__global__ __launch_bounds__(256)
void gemm_mfma(const void* __restrict__ Ap, const float* __restrict__ Wp,
               const float* __restrict__ bias,
               void* __restrict__ Y0p, void* __restrict__ Y1p,
               int M, int N) {
    const int K = 1024;
    __shared__ u16 sA[2][128 * 40];   // [0]=hi, [1]=lo
    __shared__ u16 sB[2][128 * 40];

    const int t = threadIdx.x;
    const int lane = t & 63;
    const int w = t >> 6;
    const int wm = w >> 1, wn = w & 1;
    const int rowBase = blockIdx.y * 128;
    const int colBase = blockIdx.x * 128;
    const int srow = t >> 1;          // 0..127
    const int sc = (t & 1) * 16;      // element offset 0/16

    const float* Af = (const float*)Ap;
    const u16* Au = (const u16*)Ap;

    f32x4 acc[4][4];
#pragma unroll
    for (int i = 0; i < 4; ++i)
#pragma unroll
        for (int j = 0; j < 4; ++j) acc[i][j] = (f32x4){0.f, 0.f, 0.f, 0.f};

    float ax[16], bx[16];
    u16x8 au0, au1;

    // ---- preload k0 = 0
    {
        const int k0 = 0;
        if constexpr (A_BF16) {
            au0 = *(const u16x8*)&Au[(size_t)(rowBase + srow) * K + k0 + sc];
            au1 = *(const u16x8*)&Au[(size_t)(rowBase + srow) * K + k0 + sc + 8];
        } else {
#pragma unroll
            for (int j = 0; j < 4; ++j)
                *(float4*)&ax[j * 4] = *(const float4*)&Af[(size_t)(rowBase + srow) * K + k0 + sc + j * 4];
        }
#pragma unroll
        for (int j = 0; j < 4; ++j)
            *(float4*)&bx[j * 4] = *(const float4*)&Wp[(size_t)(colBase + srow) * K + k0 + sc + j * 4];
    }

    for (int k0 = 0; k0 < K; k0 += 32) {
        __syncthreads();   // prior compute done with LDS
        // ---- write staged regs to LDS (cvt to bf16 hi/lo)
        {
            u16x8 h0, h1, l0, l1;
            if constexpr (A_BF16) {
                h0 = au0; h1 = au1;
            } else {
#pragma unroll
                for (int j = 0; j < 8; ++j) {
                    h0[j] = f2bf(ax[j]); h1[j] = f2bf(ax[j + 8]);
                    if constexpr (SPLIT) {
                        l0[j] = f2bf(ax[j] - bf2f(h0[j]));
                        l1[j] = f2bf(ax[j + 8] - bf2f(h1[j]));
                    }
                }
            }
            *(u16x8*)&sA[0][srow * 40 + sc] = h0;
            *(u16x8*)&sA[0][srow * 40 + sc + 8] = h1;
            if constexpr (SPLIT) {
                *(u16x8*)&sA[1][srow * 40 + sc] = l0;
                *(u16x8*)&sA[1][srow * 40 + sc + 8] = l1;
            }
            u16x8 bh0, bh1, bl0, bl1;
#pragma unroll
            for (int j = 0; j < 8; ++j) {
                bh0[j] = f2bf(bx[j]); bh1[j] = f2bf(bx[j + 8]);
                if constexpr (SPLIT) {
                    bl0[j] = f2bf(bx[j] - bf2f(bh0[j]));
                    bl1[j] = f2bf(bx[j + 8] - bf2f(bh1[j]));
                }
            }
            *(u16x8*)&sB[0][srow * 40 + sc] = bh0;
            *(u16x8*)&sB[0][srow * 40 + sc + 8] = bh1;
            if constexpr (SPLIT) {
                *(u16x8*)&sB[1][srow * 40 + sc] = bl0;
                *(u16x8*)&sB[1][srow * 40 + sc + 8] = bl1;
            }
        }
        __syncthreads();
        // ---- issue next-step global loads (overlap with compute)
        if (k0 + 32 < K) {
            const int kn = k0 + 32;
            if constexpr (A_BF16) {
                au0 = *(const u16x8*)&Au[(size_t)(rowBase + srow) * K + kn + sc];
                au1 = *(const u16x8*)&Au[(size_t)(rowBase + srow) * K + kn + sc + 8];
            } else {
#pragma unroll
                for (int j = 0; j < 4; ++j)
                    *(float4*)&ax[j * 4] = *(const float4*)&Af[(size_t)(rowBase + srow) * K + kn + sc + j * 4];
            }
#pragma unroll
            for (int j = 0; j < 4; ++j)
                *(float4*)&bx[j * 4] = *(const float4*)&Wp[(size_t)(colBase + srow) * K + kn + sc + j * 4];
        }
        // ---- compute: frags + MFMA
        {
            s16x8 afh[4], afl[4], bfh[4], bfl[4];
#pragma unroll
            for (int mi = 0; mi < 4; ++mi) {
                int ar = wm * 64 + mi * 16 + (lane & 15);
                int ai = ar * 40 + (lane >> 4) * 8;
                afh[mi] = *(const s16x8*)&sA[0][ai];
                if constexpr (SPLIT) afl[mi] = *(const s16x8*)&sA[1][ai];
            }
#pragma unroll
            for (int ni = 0; ni < 4; ++ni) {
                int br = wn * 64 + ni * 16 + (lane & 15);
                int bi = br * 40 + (lane >> 4) * 8;
                bfh[ni] = *(const s16x8*)&sB[0][bi];
                if constexpr (SPLIT) bfl[ni] = *(const s16x8*)&sB[1][bi];
            }
#pragma unroll
            for (int mi = 0; mi < 4; ++mi)
#pragma unroll
                for (int ni = 0; ni < 4; ++ni) {
                    acc[mi][ni] = mfma16(afh[mi], bfh[ni], acc[mi][ni]);
                    if constexpr (SPLIT) {
                        acc[mi][ni] = mfma16(afh[mi], bfl[ni], acc[mi][ni]);
                        acc[mi][ni] = mfma16(afl[mi], bfh[ni], acc[mi][ni]);
                    }
                }
        }
    }

    // ---- epilogue: D layout col=lane&15, row=(lane>>4)*4+rr
#pragma unroll
    for (int mi = 0; mi < 4; ++mi)
#pragma unroll
        for (int ni = 0; ni < 4; ++ni)
#pragma unroll
            for (int rr = 0; rr < 4; ++rr) {
                int mg = rowBase + wm * 64 + mi * 16 + (lane >> 4) * 4 + rr;
                int ng = colBase + wn * 64 + ni * 16 + (lane & 15);
                float y = acc[mi][ni][rr];
                if constexpr (OUT_MODE == 0) {
                    ((float*)Y0p)[(size_t)mg * N + ng] = y + bias[ng];
                } else if constexpr (OUT_MODE == 1) {
                    y += bias[ng];
                    u16 h = f2bf(y);
                    ((u16*)Y0p)[(size_t)mg * N + ng] = h;
                    ((u16*)Y1p)[(size_t)mg * N + ng] = f2bf(y - bf2f(h));
                } else {
                    y += bias[mg];
                    ((u16*)Y0p)[(size_t)mg * N + ng] = f2bf(y);
                }
            }
}

// ---------------------------------------------------------------------------
// Fused attention. Block = (batch, 16 q-rows), 512 thr (8 waves), heads looped.
// Per chunk: 128 k-cols; wave w owns k-cols w*16..+15 for QK^T (split-bf16,
// 6 MFMA), then wave (ks=w>>1, dh=w&1) does PV over k-slice ks*32 with V^T.
// e-values and mean accumulator live in registers; l via shfl+LDS reduce.
// K/V staged by global_load_lds with XOR-swizzled *source* (linear LDS dest).
// ---------------------------------------------------------------------------
#define CH 128
#define NCH 16

__device__ __forceinline__ void stage_kv(const u16* __restrict__ Khi,
                                         const u16* __restrict__ Klo,
                                         const u16* __restrict__ VT,
                                         u16* dKh, u16* dKl, u16* dVT,
                                         int b, int h, int kc, int w, int lane) {
#pragma unroll
    for (int i = 0; i < 2; ++i) {
        int r = w * 16 + i * 8 + (lane >> 3);      // local k-row 0..127
        int gs = lane & 7;                          // dest 16B-chunk in row
        size_t goff = (size_t)(b * SKL + kc + r) * EMBED + h * HDIM + ((gs ^ (r & 7)) << 3);
        gload16(&Khi[goff], &dKh[(w * 16 + i * 8) * 64]);
        gload16(&Klo[goff], &dKl[(w * 16 + i * 8) * 64]);
    }
#pragma unroll
    for (int i = 0; i < 2; ++i) {
        int dr = w * 8 + i * 4 + (lane >> 4);      // d-row 0..63
        int gs = lane & 15;                         // dest 16B-chunk in row
        size_t goff = (size_t)(h * HDIM + dr) * (size_t)(BATCH * SKL) + b * SKL + kc + ((gs ^ (dr & 7)) << 3);
        gload16(&VT[goff], &dVT[(w * 8 + i * 4) * 128]);
    }
}

__global__ __launch_bounds__(512)
void attn_mfma(const u16* __restrict__ Qhi, const u16* __restrict__ Qlo,
               const u16* __restrict__ Khi, const u16* __restrict__ Klo,
               const u16* __restrict__ VT, u16* __restrict__ attOut,
               float* __restrict__ meanOut) {
    __shared__ u16 sKh[2][128 * 64];
    __shared__ u16 sKl[2][128 * 64];
    __shared__ u16 sVT[2][64 * 128];
    __shared__ u16 sP[2][16 * 128];
    __shared__ float sAtt[4][16 * 64];
    __shared__ float sL[8][16];

    const int t = threadIdx.x;
    const int w = t >> 6;
    const int lane = t & 63;
    const int qg = lane >> 4;      // 0..3
    const int c16 = lane & 15;
    const int b = blockIdx.x >> 6;
    const int qbase = (blockIdx.x & 63) * 16;
    const int ks = w >> 1;         // PV k-slice 0..3
    const int dh2 = w & 1;         // PV d-half

    float meanacc[4][16];
#pragma unroll
    for (int r4 = 0; r4 < 4; ++r4)
#pragma unroll
        for (int c = 0; c < NCH; ++c) meanacc[r4][c] = 0.f;

    for (int h = 0; h < NHEADS; ++h) {
        // Q fragments (A-frag: m=lane&15 row, kk=(lane>>4)*8+j)
        s16x8 qh[2], ql[2];
#pragma unroll
        for (int dh = 0; dh < 2; ++dh) {
            size_t qoff = (size_t)(b * SQL + qbase + c16) * EMBED + h * HDIM + dh * 32 + qg * 8;
            qh[dh] = *(const s16x8*)&Qhi[qoff];
            ql[dh] = *(const s16x8*)&Qlo[qoff];
        }
        f32x4 pv0 = {0.f, 0.f, 0.f, 0.f}, pv1 = {0.f, 0.f, 0.f, 0.f};
        float ev[4][NCH];

        stage_kv(Khi, Klo, VT, &sKh[0][0], &sKl[0][0], &sVT[0][0], b, h, 0, w, lane);
        __syncthreads();

#pragma unroll
        for (int c = 0; c < NCH; ++c) {
            const int buf = c & 1;
            if (c + 1 < NCH)
                stage_kv(Khi, Klo, VT, &sKh[buf ^ 1][0], &sKl[buf ^ 1][0], &sVT[buf ^ 1][0],
                         b, h, (c + 1) * CH, w, lane);
            // ---- QK^T (split): S = Qhi*Khi + Qhi*Klo + Qlo*Khi
            f32x4 s = {0.f, 0.f, 0.f, 0.f};
            {
                int r = w * 16 + c16;                // K row for B-frag (n = lane&15)
                int base = r * 64;
                int sw0 = ((qg) ^ (r & 7)) << 3;      // d-chunk qg  (dh=0)
                int sw1 = ((qg + 4) ^ (r & 7)) << 3;  // d-chunk qg+4 (dh=1)
                s16x8 kh0 = *(const s16x8*)&sKh[buf][base + sw0];
                s16x8 kh1 = *(const s16x8*)&sKh[buf][base + sw1];
                s16x8 kl0 = *(const s16x8*)&sKl[buf][base + sw0];
                s16x8 kl1 = *(const s16x8*)&sKl[buf][base + sw1];
                s = mfma16(qh[0], kh0, s);
                s = mfma16(qh[1], kh1, s);
                s = mfma16(qh[0], kl0, s);
                s = mfma16(qh[1], kl1, s);
                s = mfma16(ql[0], kh0, s);
                s = mfma16(ql[1], kh1, s);
            }
            // ---- e = exp(s*scale); keep in regs; write bf16 P to LDS (swizzled)
            {
                const int pcol = w * 16 + c16;
                const int pch = pcol >> 3;
                const int plow = pcol & 7;
#pragma unroll
                for (int r4 = 0; r4 < 4; ++r4) {
                    int q = qg * 4 + r4;
                    float e = __expf(s[r4] * 0.125f);
                    ev[r4][c] = e;
                    sP[buf][q * 128 + ((pch ^ (q & 7)) << 3) + plow] = f2bf(e);
                }
            }
            asm volatile("s_waitcnt lgkmcnt(0)" ::: "memory");
            __builtin_amdgcn_sched_barrier(0);
            __builtin_amdgcn_s_barrier();            // P visible; staging still in flight
            // ---- PV: wave (ks, dh2): attended[16q x 32d] over k-slice ks*32..+31
            {
                int pidx = c16 * 128 + (((ks * 4 + qg) ^ (c16 & 7)) << 3);
                s16x8 pa = *(const s16x8*)&sP[buf][pidx];
                int dr0 = dh2 * 32 + c16;
                int dr1 = dh2 * 32 + 16 + c16;
                s16x8 v0 = *(const s16x8*)&sVT[buf][dr0 * 128 + (((ks * 4 + qg) ^ (dr0 & 7)) << 3)];
                s16x8 v1 = *(const s16x8*)&sVT[buf][dr1 * 128 + (((ks * 4 + qg) ^ (dr1 & 7)) << 3)];
                pv0 = mfma16(pa, v0, pv0);
                pv1 = mfma16(pa, v1, pv1);
            }
            __syncthreads();                          // drains staging vmcnt too
        }

        // ---- head epilogue: l reduce (sum over k)
        {
            float ls[4];
#pragma unroll
            for (int r4 = 0; r4 < 4; ++r4) {
                float v = 0.f;
#pragma unroll
                for (int c = 0; c < NCH; ++c) v += ev[r4][c];
#pragma unroll
                for (int m = 1; m <= 8; m <<= 1) v += __shfl_xor(v, m, 64);
                ls[r4] = v;
            }
            if (c16 == 0) {
#pragma unroll
                for (int r4 = 0; r4 < 4; ++r4) sL[w][qg * 4 + r4] = ls[r4];
            }
        }
        // attended partials -> LDS
#pragma unroll
        for (int r4 = 0; r4 < 4; ++r4) {
            sAtt[ks][(qg * 4 + r4) * 64 + dh2 * 32 + c16] = pv0[r4];
            sAtt[ks][(qg * 4 + r4) * 64 + dh2 * 32 + 16 + c16] = pv1[r4];
        }
        __syncthreads();
        // attended write (bf16)
        {
            int q = t >> 5;
            int d0 = (t & 31) * 2;
            float l = sL[0][q] + sL[1][q] + sL[2][q] + sL[3][q] +
                      sL[4][q] + sL[5][q] + sL[6][q] + sL[7][q];
            float linv = 1.f / l;
            float a0 = sAtt[0][q * 64 + d0] + sAtt[1][q * 64 + d0] +
                       sAtt[2][q * 64 + d0] + sAtt[3][q * 64 + d0];
            float a1 = sAtt[0][q * 64 + d0 + 1] + sAtt[1][q * 64 + d0 + 1] +
                       sAtt[2][q * 64 + d0 + 1] + sAtt[3][q * 64 + d0 + 1];
            size_t o = (size_t)(b * SQL + qbase + q) * EMBED + h * HDIM + d0;
            attOut[o] = f2bf(a0 * linv);
            attOut[o + 1] = f2bf(a1 * linv);
        }
        // mean accumulation (registers)
#pragma unroll
        for (int r4 = 0; r4 < 4; ++r4) {
            int q = qg * 4 + r4;
            float l = sL[0][q] + sL[1][q] + sL[2][q] + sL[3][q] +
                      sL[4][q] + sL[5][q] + sL[6][q] + sL[7][q];
            float linv = 1.f / l;
#pragma unroll
            for (int c = 0; c < NCH; ++c) meanacc[r4][c] += ev[r4][c] * linv;
        }
        __syncthreads();
    }

    // ---- final mean write
    const float s16c = 1.f / 16.f;
#pragma unroll
    for (int r4 = 0; r4 < 4; ++r4)
#pragma unroll
        for (int c = 0; c < NCH; ++c)
            meanOut[(size_t)(b * SQL + qbase + qg * 4 + r4) * SKL + c * CH + w * 16 + c16] =
                meanacc[r4][c] * s16c;
}

// ---------------------------------------------------------------------------
extern "C" void kernel_launch(void* const* d_in, const int* in_sizes, int n_in,
                              void* d_out, int out_size, void* d_ws, size_t ws_size,
                              hipStream_t stream) {
    const float* query = (const float*)d_in[0];
    const float* key   = (const float*)d_in[1];
    const float* value = (const float*)d_in[2];
    const float* Wq = (const float*)d_in[3];
    const float* bq = (const float*)d_in[4];
    const float* Wk = (const float*)d_in[5];
    const float* bk = (const float*)d_in[6];
    const float* Wv = (const float*)d_in[7];
    const float* bv = (const float*)d_in[8];
    const float* Wo = (const float*)d_in[9];
    const float* bo = (const float*)d_in[10];

    float* out = (float*)d_out;                         // [4,1024,1024]
    float* meanOut = out + (size_t)BATCH * SQL * EMBED; // [4,1024,2048]

    u16* Qhi = (u16*)d_ws;                              // [4096][1024] bf16
    u16* Qlo = Qhi + (size_t)4096 * 1024;
    u16* Khi = Qlo + (size_t)4096 * 1024;               // [8192][1024]
    u16* Klo = Khi + (size_t)8192 * 1024;
    u16* VTw = Klo + (size_t)8192 * 1024;               // [1024][8192] (V^T)
    u16* Att = VTw + (size_t)1024 * 8192;               // [4096][1024] bf16

    // Q, K projections: split-bf16 (fp32-accurate), emit hi/lo planes
    gemm_mfma<1, 0, 1><<<dim3(8, 32), 256, 0, stream>>>(query, Wq, bq, Qhi, Qlo, 4096, 1024);
    gemm_mfma<1, 0, 1><<<dim3(8, 64), 256, 0, stream>>>(key, Wk, bk, Khi, Klo, 8192, 1024);
    // V projection, transposed output: VT[e][token] = Wv[e]·value[token] + bv[e]
    gemm_mfma<0, 0, 2><<<dim3(64, 8), 256, 0, stream>>>(Wv, value, bv, VTw, nullptr, 1024, 8192);
    // fused attention
    attn_mfma<<<dim3(256), dim3(512), 0, stream>>>(Qhi, Qlo, Khi, Klo, VTw, Att, meanOut);
    // output projection (A bf16)
    gemm_mfma<0, 1, 0><<<dim3(8, 32), 256, 0, stream>>>(Att, Wo, bo, out, nullptr, 4096, 1024);
}

// Round 3
// 544.554 us; speedup vs baseline: 4.5170x; 1.1411x over previous
//
#include <hip/hip_runtime.h>
#include <hip/hip_bf16.h>
#include <math.h>

#define EMBED 1024
#define NHEADS 16
#define HDIM 64
#define BATCH 4
#define SQL 1024
#define SKL 2048

typedef unsigned short u16;
typedef __attribute__((ext_vector_type(4))) float f32x4;
typedef __attribute__((ext_vector_type(8))) __bf16 bf16x8;
typedef __attribute__((ext_vector_type(8))) short s16x8;
typedef __attribute__((ext_vector_type(8))) u16 u16x8;

__device__ __forceinline__ u16 f2bf(float x) {
    __hip_bfloat16 h = __float2bfloat16(x);
    return *reinterpret_cast<u16*>(&h);
}
__device__ __forceinline__ float bf2f(u16 u) {
    __hip_bfloat16 h;
    *reinterpret_cast<u16*>(&h) = u;
    return __bfloat162float(h);
}
__device__ __forceinline__ f32x4 mfma16(s16x8 a, s16x8 b, f32x4 c) {
    return __builtin_amdgcn_mfma_f32_16x16x32_bf16(
        __builtin_bit_cast(bf16x8, a), __builtin_bit_cast(bf16x8, b), c, 0, 0, 0);
}

// ---------------------------------------------------------------------------
// GEMM NT (unchanged from round 2): Y[M,N] = A[M,K] * W[N,K]^T + bias. K=1024.
// ---------------------------------------------------------------------------
template<int SPLIT, int A_BF16, int OUT_MODE>
__global__ __launch_bounds__(256)
void gemm_mfma(const void* __restrict__ Ap, const float* __restrict__ Wp,
               const float* __restrict__ bias,
               void* __restrict__ Y0p, void* __restrict__ Y1p,
               int M, int N) {
    const int K = 1024;
    __shared__ u16 sA[2][128 * 40];
    __shared__ u16 sB[2][128 * 40];

    const int t = threadIdx.x;
    const int lane = t & 63;
    const int w = t >> 6;
    const int wm = w >> 1, wn = w & 1;
    const int rowBase = blockIdx.y * 128;
    const int colBase = blockIdx.x * 128;
    const int srow = t >> 1;
    const int sc = (t & 1) * 16;

    const float* Af = (const float*)Ap;
    const u16* Au = (const u16*)Ap;

    f32x4 acc[4][4];
#pragma unroll
    for (int i = 0; i < 4; ++i)
#pragma unroll
        for (int j = 0; j < 4; ++j) acc[i][j] = (f32x4){0.f, 0.f, 0.f, 0.f};

    float ax[16], bx[16];
    u16x8 au0, au1;

    {
        const int k0 = 0;
        if constexpr (A_BF16) {
            au0 = *(const u16x8*)&Au[(size_t)(rowBase + srow) * K + k0 + sc];
            au1 = *(const u16x8*)&Au[(size_t)(rowBase + srow) * K + k0 + sc + 8];
        } else {
#pragma unroll
            for (int j = 0; j < 4; ++j)
                *(float4*)&ax[j * 4] = *(const float4*)&Af[(size_t)(rowBase + srow) * K + k0 + sc + j * 4];
        }
#pragma unroll
        for (int j = 0; j < 4; ++j)
            *(float4*)&bx[j * 4] = *(const float4*)&Wp[(size_t)(colBase + srow) * K + k0 + sc + j * 4];
    }

    for (int k0 = 0; k0 < K; k0 += 32) {
        __syncthreads();
        {
            u16x8 h0, h1, l0, l1;
            if constexpr (A_BF16) {
                h0 = au0; h1 = au1;
            } else {
#pragma unroll
                for (int j = 0; j < 8; ++j) {
                    h0[j] = f2bf(ax[j]); h1[j] = f2bf(ax[j + 8]);
                    if constexpr (SPLIT) {
                        l0[j] = f2bf(ax[j] - bf2f(h0[j]));
                        l1[j] = f2bf(ax[j + 8] - bf2f(h1[j]));
                    }
                }
            }
            *(u16x8*)&sA[0][srow * 40 + sc] = h0;
            *(u16x8*)&sA[0][srow * 40 + sc + 8] = h1;
            if constexpr (SPLIT) {
                *(u16x8*)&sA[1][srow * 40 + sc] = l0;
                *(u16x8*)&sA[1][srow * 40 + sc + 8] = l1;
            }
            u16x8 bh0, bh1, bl0, bl1;
#pragma unroll
            for (int j = 0; j < 8; ++j) {
                bh0[j] = f2bf(bx[j]); bh1[j] = f2bf(bx[j + 8]);
                if constexpr (SPLIT) {
                    bl0[j] = f2bf(bx[j] - bf2f(bh0[j]));
                    bl1[j] = f2bf(bx[j + 8] - bf2f(bh1[j]));
                }
            }
            *(u16x8*)&sB[0][srow * 40 + sc] = bh0;
            *(u16x8*)&sB[0][srow * 40 + sc + 8] = bh1;
            if constexpr (SPLIT) {
                *(u16x8*)&sB[1][srow * 40 + sc] = bl0;
                *(u16x8*)&sB[1][srow * 40 + sc + 8] = bl1;
            }
        }
        __syncthreads();
        if (k0 + 32 < K) {
            const int kn = k0 + 32;
            if constexpr (A_BF16) {
                au0 = *(const u16x8*)&Au[(size_t)(rowBase + srow) * K + kn + sc];
                au1 = *(const u16x8*)&Au[(size_t)(rowBase + srow) * K + kn + sc + 8];
            } else {
#pragma unroll
                for (int j = 0; j < 4; ++j)
                    *(float4*)&ax[j * 4] = *(const float4*)&Af[(size_t)(rowBase + srow) * K + kn + sc + j * 4];
            }
#pragma unroll
            for (int j = 0; j < 4; ++j)
                *(float4*)&bx[j * 4] = *(const float4*)&Wp[(size_t)(colBase + srow) * K + kn + sc + j * 4];
        }
        {
            s16x8 afh[4], afl[4], bfh[4], bfl[4];
#pragma unroll
            for (int mi = 0; mi < 4; ++mi) {
                int ar = wm * 64 + mi * 16 + (lane & 15);
                int ai = ar * 40 + (lane >> 4) * 8;
                afh[mi] = *(const s16x8*)&sA[0][ai];
                if constexpr (SPLIT) afl[mi] = *(const s16x8*)&sA[1][ai];
            }
#pragma unroll
            for (int ni = 0; ni < 4; ++ni) {
                int br = wn * 64 + ni * 16 + (lane & 15);
                int bi = br * 40 + (lane >> 4) * 8;
                bfh[ni] = *(const s16x8*)&sB[0][bi];
                if constexpr (SPLIT) bfl[ni] = *(const s16x8*)&sB[1][bi];
            }
#pragma unroll
            for (int mi = 0; mi < 4; ++mi)
#pragma unroll
                for (int ni = 0; ni < 4; ++ni) {
                    acc[mi][ni] = mfma16(afh[mi], bfh[ni], acc[mi][ni]);
                    if constexpr (SPLIT) {
                        acc[mi][ni] = mfma16(afh[mi], bfl[ni], acc[mi][ni]);
                        acc[mi][ni] = mfma16(afl[mi], bfh[ni], acc[mi][ni]);
                    }
                }
        }
    }

#pragma unroll
    for (int mi = 0; mi < 4; ++mi)
#pragma unroll
        for (int ni = 0; ni < 4; ++ni)
#pragma unroll
            for (int rr = 0; rr < 4; ++rr) {
                int mg = rowBase + wm * 64 + mi * 16 + (lane >> 4) * 4 + rr;
                int ng = colBase + wn * 64 + ni * 16 + (lane & 15);
                float y = acc[mi][ni][rr];
                if constexpr (OUT_MODE == 0) {
                    ((float*)Y0p)[(size_t)mg * N + ng] = y + bias[ng];
                } else if constexpr (OUT_MODE == 1) {
                    y += bias[ng];
                    u16 h = f2bf(y);
                    ((u16*)Y0p)[(size_t)mg * N + ng] = h;
                    ((u16*)Y1p)[(size_t)mg * N + ng] = f2bf(y - bf2f(h));
                } else {
                    y += bias[mg];
                    ((u16*)Y0p)[(size_t)mg * N + ng] = f2bf(y);
                }
            }
}

// ---------------------------------------------------------------------------
// Fused attention, register-direct K/V (no K/V LDS staging).
// Block = (b, 16 q-rows), 512 thr (8 waves), heads looped, chunks of 128 k.
// Per chunk per wave: 4 K-frag + 2 V-frag global loads (prefetched 1 chunk
// ahead into alternate named reg sets), 6 QK^T MFMA (split bf16), exp,
// bf16 P -> LDS (XOR-swizzled), ONE raw s_barrier (lgkmcnt-only wait, vmcnt
// prefetches stay in flight), 2 PV MFMA. e and mean stay in registers.
// ---------------------------------------------------------------------------
#define CH 128
#define NCH 16

#define LOADK(d0, d1, d2, d3, c) { \
    size_t _o = kbase0 + (size_t)(c) * (CH * EMBED); \
    d0 = *(const s16x8*)&Khi[_o];      d1 = *(const s16x8*)&Khi[_o + 32]; \
    d2 = *(const s16x8*)&Klo[_o];      d3 = *(const s16x8*)&Klo[_o + 32]; }

#define LOADV(d0, d1, c) { \
    size_t _o = vbase0 + (size_t)(c) * CH; \
    d0 = *(const s16x8*)&VT[_o]; \
    d1 = *(const s16x8*)&VT[_o + (size_t)16 * (BATCH * SKL)]; }

#define CHUNK(c, k0, k1, k2, k3, v0, v1) { \
    f32x4 s = {0.f, 0.f, 0.f, 0.f}; \
    s = mfma16(qh0, k0, s); \
    s = mfma16(qh1, k1, s); \
    s = mfma16(qh0, k2, s); \
    s = mfma16(qh1, k3, s); \
    s = mfma16(ql0, k0, s); \
    s = mfma16(ql1, k1, s); \
    _Pragma("unroll") \
    for (int r4 = 0; r4 < 4; ++r4) { \
        int q = qg * 4 + r4; \
        float e = __expf(s[r4] * 0.125f); \
        ev[r4][c] = e; \
        sP[(c) & 1][q * 128 + ((pch ^ (q & 7)) << 3) + plow] = f2bf(e); \
    } \
    asm volatile("s_waitcnt lgkmcnt(0)" ::: "memory"); \
    __builtin_amdgcn_sched_barrier(0); \
    __builtin_amdgcn_s_barrier(); \
    __builtin_amdgcn_sched_barrier(0); \
    { \
        s16x8 pa = *(const s16x8*)&sP[(c) & 1][pidx]; \
        pv0 = mfma16(pa, v0, pv0); \
        pv1 = mfma16(pa, v1, pv1); \
    } }

__global__ __launch_bounds__(512, 1)
void attn_mfma(const u16* __restrict__ Qhi, const u16* __restrict__ Qlo,
               const u16* __restrict__ Khi, const u16* __restrict__ Klo,
               const u16* __restrict__ VT, u16* __restrict__ attOut,
               float* __restrict__ meanOut) {
    __shared__ u16 sP[2][16 * 128];      // 8 KB
    __shared__ float sAtt[4][16 * 64];   // 16 KB
    __shared__ float sL[8][16];

    const int t = threadIdx.x;
    const int w = t >> 6;
    const int lane = t & 63;
    const int qg = lane >> 4;       // 0..3
    const int c16 = lane & 15;
    const int b = blockIdx.x >> 6;
    const int qbase = (blockIdx.x & 63) * 16;
    const int ks = w >> 1;          // PV k-slice 0..3
    const int dh2 = w & 1;          // PV d-half

    // P LDS addressing (constant per thread)
    const int pcol = w * 16 + c16;
    const int pch = pcol >> 3;
    const int plow = pcol & 7;
    const int pidx = c16 * 128 + (((ks * 4 + qg) ^ (c16 & 7)) << 3);

    float meanacc[4][NCH];
#pragma unroll
    for (int r4 = 0; r4 < 4; ++r4)
#pragma unroll
        for (int c = 0; c < NCH; ++c) meanacc[r4][c] = 0.f;

    for (int h = 0; h < NHEADS; ++h) {
        // Q fragments (A-frag: q-row = c16, k-pos = qg*8+j, d = dh*32+qg*8+j)
        size_t qoff = (size_t)(b * SQL + qbase + c16) * EMBED + h * HDIM + qg * 8;
        s16x8 qh0 = *(const s16x8*)&Qhi[qoff];
        s16x8 qh1 = *(const s16x8*)&Qhi[qoff + 32];
        s16x8 ql0 = *(const s16x8*)&Qlo[qoff];
        s16x8 ql1 = *(const s16x8*)&Qlo[qoff + 32];

        // per-wave global base offsets
        const size_t kbase0 = (size_t)(b * SKL + w * 16 + c16) * EMBED + h * HDIM + qg * 8;
        const size_t vbase0 = (size_t)(h * HDIM + dh2 * 32 + c16) * (size_t)(BATCH * SKL)
                              + (size_t)b * SKL + ks * 32 + qg * 8;

        f32x4 pv0 = {0.f, 0.f, 0.f, 0.f}, pv1 = {0.f, 0.f, 0.f, 0.f};
        float ev[4][NCH];

        s16x8 ka0, ka1, ka2, ka3, kb0, kb1, kb2, kb3;
        s16x8 va0, va1, vb0, vb1;

        LOADK(ka0, ka1, ka2, ka3, 0)
        LOADV(va0, va1, 0)

#pragma unroll
        for (int cc = 0; cc < NCH; cc += 2) {
            LOADK(kb0, kb1, kb2, kb3, cc + 1)
            LOADV(vb0, vb1, cc + 1)
            CHUNK(cc, ka0, ka1, ka2, ka3, va0, va1)
            if (cc + 2 < NCH) {
                LOADK(ka0, ka1, ka2, ka3, cc + 2)
                LOADV(va0, va1, cc + 2)
            }
            CHUNK(cc + 1, kb0, kb1, kb2, kb3, vb0, vb1)
        }

        // ---- head epilogue: l reduce over the 16 k-lanes of each wave
        {
            float ls[4];
#pragma unroll
            for (int r4 = 0; r4 < 4; ++r4) {
                float v = 0.f;
#pragma unroll
                for (int c = 0; c < NCH; ++c) v += ev[r4][c];
#pragma unroll
                for (int m = 1; m <= 8; m <<= 1) v += __shfl_xor(v, m, 64);
                ls[r4] = v;
            }
            if (c16 == 0) {
#pragma unroll
                for (int r4 = 0; r4 < 4; ++r4) sL[w][qg * 4 + r4] = ls[r4];
            }
        }
        // attended partials -> LDS
#pragma unroll
        for (int r4 = 0; r4 < 4; ++r4) {
            sAtt[ks][(qg * 4 + r4) * 64 + dh2 * 32 + c16] = pv0[r4];
            sAtt[ks][(qg * 4 + r4) * 64 + dh2 * 32 + 16 + c16] = pv1[r4];
        }
        __syncthreads();
        // attended write (bf16)
        {
            int q = t >> 5;
            int d0 = (t & 31) * 2;
            float l = sL[0][q] + sL[1][q] + sL[2][q] + sL[3][q] +
                      sL[4][q] + sL[5][q] + sL[6][q] + sL[7][q];
            float linv = 1.f / l;
            float a0 = sAtt[0][q * 64 + d0] + sAtt[1][q * 64 + d0] +
                       sAtt[2][q * 64 + d0] + sAtt[3][q * 64 + d0];
            float a1 = sAtt[0][q * 64 + d0 + 1] + sAtt[1][q * 64 + d0 + 1] +
                       sAtt[2][q * 64 + d0 + 1] + sAtt[3][q * 64 + d0 + 1];
            size_t o = (size_t)(b * SQL + qbase + q) * EMBED + h * HDIM + d0;
            attOut[o] = f2bf(a0 * linv);
            attOut[o + 1] = f2bf(a1 * linv);
        }
        // mean accumulation (registers)
#pragma unroll
        for (int r4 = 0; r4 < 4; ++r4) {
            int q = qg * 4 + r4;
            float l = sL[0][q] + sL[1][q] + sL[2][q] + sL[3][q] +
                      sL[4][q] + sL[5][q] + sL[6][q] + sL[7][q];
            float linv = 1.f / l;
#pragma unroll
            for (int c = 0; c < NCH; ++c) meanacc[r4][c] += ev[r4][c] * linv;
        }
    }

    // ---- final mean write
    const float s16c = 1.f / 16.f;
#pragma unroll
    for (int r4 = 0; r4 < 4; ++r4)
#pragma unroll
        for (int c = 0; c < NCH; ++c)
            meanOut[(size_t)(b * SQL + qbase + qg * 4 + r4) * SKL + c * CH + w * 16 + c16] =
                meanacc[r4][c] * s16c;
}

// ---------------------------------------------------------------------------
extern "C" void kernel_launch(void* const* d_in, const int* in_sizes, int n_in,
                              void* d_out, int out_size, void* d_ws, size_t ws_size,
                              hipStream_t stream) {
    const float* query = (const float*)d_in[0];
    const float* key   = (const float*)d_in[1];
    const float* value = (const float*)d_in[2];
    const float* Wq = (const float*)d_in[3];
    const float* bq = (const float*)d_in[4];
    const float* Wk = (const float*)d_in[5];
    const float* bk = (const float*)d_in[6];
    const float* Wv = (const float*)d_in[7];
    const float* bv = (const float*)d_in[8];
    const float* Wo = (const float*)d_in[9];
    const float* bo = (const float*)d_in[10];

    float* out = (float*)d_out;                         // [4,1024,1024]
    float* meanOut = out + (size_t)BATCH * SQL * EMBED; // [4,1024,2048]

    u16* Qhi = (u16*)d_ws;                              // [4096][1024] bf16
    u16* Qlo = Qhi + (size_t)4096 * 1024;
    u16* Khi = Qlo + (size_t)4096 * 1024;               // [8192][1024]
    u16* Klo = Khi + (size_t)8192 * 1024;
    u16* VTw = Klo + (size_t)8192 * 1024;               // [1024][8192] (V^T)
    u16* Att = VTw + (size_t)1024 * 8192;               // [4096][1024] bf16

    gemm_mfma<1, 0, 1><<<dim3(8, 32), 256, 0, stream>>>(query, Wq, bq, Qhi, Qlo, 4096, 1024);
    gemm_mfma<1, 0, 1><<<dim3(8, 64), 256, 0, stream>>>(key, Wk, bk, Khi, Klo, 8192, 1024);
    gemm_mfma<0, 0, 2><<<dim3(64, 8), 256, 0, stream>>>(Wv, value, bv, VTw, nullptr, 1024, 8192);
    attn_mfma<<<dim3(256), dim3(512), 0, stream>>>(Qhi, Qlo, Khi, Klo, VTw, Att, meanOut);
    gemm_mfma<0, 1, 0><<<dim3(8, 32), 256, 0, stream>>>(Att, Wo, bo, out, nullptr, 4096, 1024);
}